// Round 5
// baseline (30.779 us; speedup 1.0000x reference)
//
#include <hip/hip_runtime.h>
#include <hip/hip_bf16.h>

// S=128, Q=8192, H=230
//   logits[s,q] = a[s] + (c[q]+b) - 2*sum_k (w*x)[s,k]*y[q,k]
// Single fused kernel: per block (16-q tile, all 128 s):
//   wl=w->LDS; y-tile->bf16 swizzled LDS (B operand); c[q] from LDS tile;
//   A-frags bf16(w*x) built in registers from x; a[s] via shfl_xor byproduct;
//   16x16x32 bf16 MFMA; fused sigmoid + BCE; deterministic last-block loss
//   reduction (device-scope atomics; fixed summation order -> bitwise stable).

#define S_DIM 128
#define Q_DIM 8192
#define H_DIM 230
#define K2    256
#define SQ    (S_DIM * Q_DIM)
#define QB    16
#define NBLK  (Q_DIM / QB)     // 512

using short8 = __attribute__((ext_vector_type(8))) short;   // 8 bf16
using f32x4  = __attribute__((ext_vector_type(4))) float;

__device__ __forceinline__ short bf16bits(float f) {
    __hip_bfloat16 h = __float2bfloat16(f);
    return *reinterpret_cast<short*>(&h);
}

// ---------------- Kernel 0: zero the arrival counter ----------------
__global__ void zero_cnt_kernel(unsigned* __restrict__ cnt) {
    if (threadIdx.x == 0) *cnt = 0u;
}

// ---------------- Kernel 1: fully fused ----------------
// grid = 512, block = 256 (4 waves). Block: q-tile [q0,q0+16), all 128 s.
// Wave wid: s in [32*wid, 32*wid+32): acc0 = rows +0..15, acc1 = rows +16..31.
__global__ __launch_bounds__(256) void fused_kernel(
    const float* __restrict__ x, const float* __restrict__ y,
    const int* __restrict__ label, const float* __restrict__ w,
    const float* __restrict__ bptr, float* __restrict__ out,
    float* __restrict__ lossws, unsigned* __restrict__ cnt)
{
    __shared__ __align__(16) short ylb[QB * K2];   // 8 KB bf16, XOR-swizzled
    __shared__ float wl[K2];                       // w zero-padded, f32
    __shared__ float cpart[16][17];
    __shared__ float cq[QB];
    __shared__ float asl[S_DIM];
    __shared__ float lred[4];
    __shared__ unsigned islast;

    const int tid = threadIdx.x, bid = blockIdx.x;
    const int q0 = bid * QB;
    const int wid = tid >> 6, l = tid & 63;
    const int lm = l & 15, lh = l >> 4;
    const int s0 = wid * 32;
    const int qg = q0 + lm;
    char* ylc = reinterpret_cast<char*>(ylb);

    // ---- prefetch 8 labels (rows s0 + f*16 + lh*4 + r), in flight all kernel ----
    int labs[2][4];
    #pragma unroll
    for (int f = 0; f < 2; ++f)
        #pragma unroll
        for (int r = 0; r < 4; ++r)
            labs[f][r] = label[(size_t)(s0 + f * 16 + lh * 4 + r) * Q_DIM + qg];

    // ---- w -> LDS (zero-padded to 256) ----
    wl[tid] = (tid < H_DIM) ? w[tid] : 0.0f;

    // ---- stage y tile (16 x 230 f32, one contiguous 16B-aligned span) ----
    const float4* ysrc4 = reinterpret_cast<const float4*>(y + (size_t)q0 * H_DIM);
    #pragma unroll
    for (int it = 0; it < 4; ++it) {
        int i4 = tid + 256 * it;
        if (i4 < (QB * H_DIM) / 4) {
            float4 v = ysrc4[i4];
            float vv[4] = {v.x, v.y, v.z, v.w};
            #pragma unroll
            for (int j = 0; j < 4; ++j) {
                int e = i4 * 4 + j;
                int r = e / H_DIM;
                int c = e - r * H_DIM;
                int byt = ((r << 9) + (c << 1)) ^ ((r & 7) << 4);
                *reinterpret_cast<__hip_bfloat16*>(ylc + byt) = __float2bfloat16(vv[j]);
            }
        }
    }
    {   // zero-fill k = 230..255
        const int r = tid & 15;
        for (int c = H_DIM + (tid >> 4); c < K2; c += 16) {
            int byt = ((r << 9) + (c << 1)) ^ ((r & 7) << 4);
            *reinterpret_cast<__hip_bfloat16*>(ylc + byt) = __float2bfloat16(0.0f);
        }
    }
    __syncthreads();   // ylb + wl valid

    // ---- build A fragments in registers + a[s] partials ----
    // A row for acc0: s0+lm; for acc1: s0+16+lm. k = ks*32 + lh*8 + e.
    // float2 pairs (even k, H even): pair fully valid iff k < 230.
    short8 Aa[8], Ab[8];
    float ap0 = 0.f, ap1 = 0.f;
    const float* xr0 = x + (size_t)(s0 + lm) * H_DIM;
    const float* xr1 = x + (size_t)(s0 + 16 + lm) * H_DIM;
    #pragma unroll
    for (int ks = 0; ks < 8; ++ks) {
        const int kof = ks * 32 + lh * 8;
        float x0[8], x1[8], wf[8];
        #pragma unroll
        for (int j = 0; j < 4; ++j) {
            int k = kof + 2 * j;
            float2 v0 = {0.f, 0.f}, v1 = {0.f, 0.f};
            if (k < H_DIM) {
                v0 = *reinterpret_cast<const float2*>(xr0 + k);
                v1 = *reinterpret_cast<const float2*>(xr1 + k);
            }
            x0[2*j] = v0.x; x0[2*j+1] = v0.y;
            x1[2*j] = v1.x; x1[2*j+1] = v1.y;
            wf[2*j] = wl[k]; wf[2*j+1] = wl[k + 1];
        }
        short8 a0, a1;
        #pragma unroll
        for (int j = 0; j < 8; ++j) {
            float p0 = wf[j] * x0[j];
            float p1 = wf[j] * x1[j];
            a0[j] = bf16bits(p0);
            a1[j] = bf16bits(p1);
            ap0 = fmaf(p0, x0[j], ap0);    // w*x^2 (f32 exact)
            ap1 = fmaf(p1, x1[j], ap1);
        }
        Aa[ks] = a0; Ab[ks] = a1;
    }
    // combine the 4 lh-quarters of each row's a-sum (fixed order, deterministic)
    ap0 += __shfl_xor(ap0, 16, 64); ap0 += __shfl_xor(ap0, 32, 64);
    ap1 += __shfl_xor(ap1, 16, 64); ap1 += __shfl_xor(ap1, 32, 64);
    if (lh == 0) { asl[s0 + lm] = ap0; asl[s0 + 16 + lm] = ap1; }

    // ---- c[q] = sum_k wl[k]*y~[q,k]^2 from the bf16 tile ----
    {
        const int r = tid & 15, ch = tid >> 4;
        const int k0 = ch * 16;
        float p = 0.f;
        #pragma unroll
        for (int j = 0; j < 16; ++j) {
            int k = k0 + j;
            int byt = ((r << 9) + (k << 1)) ^ ((r & 7) << 4);
            float v = __bfloat162float(*reinterpret_cast<__hip_bfloat16*>(ylc + byt));
            p = fmaf(wl[k] * v, v, p);
        }
        cpart[ch][r] = p;
    }
    __syncthreads();   // cpart + asl ready
    if (tid < QB) {
        float c = 0.f;
        #pragma unroll
        for (int ch = 0; ch < 16; ++ch) c += cpart[ch][tid];
        cq[tid] = c + bptr[0];
    }
    __syncthreads();   // cq ready

    // ---- MFMA: 8 k-steps x 2 (A regs, B from swizzled LDS) ----
    f32x4 acc0 = {0.f, 0.f, 0.f, 0.f};
    f32x4 acc1 = {0.f, 0.f, 0.f, 0.f};
    #pragma unroll
    for (int ks = 0; ks < 8; ++ks) {
        const int kof = ks * 32 + lh * 8;
        int byt = ((lm << 9) + (kof << 1)) ^ ((lm & 7) << 4);
        short8 bf = *reinterpret_cast<const short8*>(ylc + byt);
        acc0 = __builtin_amdgcn_mfma_f32_16x16x32_bf16(Aa[ks], bf, acc0, 0, 0, 0);
        acc1 = __builtin_amdgcn_mfma_f32_16x16x32_bf16(Ab[ks], bf, acc1, 0, 0, 0);
    }

    // ---- epilogue: D row=(l>>4)*4+r (s), col=lm (q) ----
    float lsum = 0.f;
    const float cqv = cq[lm];
    #pragma unroll
    for (int f = 0; f < 2; ++f) {
        f32x4 ac = f ? acc1 : acc0;
        #pragma unroll
        for (int r = 0; r < 4; ++r) {
            int s = s0 + f * 16 + lh * 4 + r;
            float z = asl[s] + cqv - 2.0f * ac[r];
            float sc = 1.0f / (1.0f + __expf(-z));
            out[(size_t)s * Q_DIM + qg] = sc;
            float lab = (float)labs[f][r];
            float bce = fmaxf(z, 0.f) - z * lab + log1pf(__expf(-fabsf(z)));
            lsum += bce;
        }
    }
    #pragma unroll
    for (int off = 32; off >= 1; off >>= 1) lsum += __shfl_down(lsum, off, 64);
    if (l == 0) lred[wid] = lsum;
    __syncthreads();

    // ---- deterministic cross-block loss: last block reduces fixed-order ----
    if (tid == 0) {
        float blk = lred[0] + lred[1] + lred[2] + lred[3];
        atomicExch(&lossws[bid], blk);          // device-scope coherent store
        __threadfence();
        unsigned old = atomicAdd(cnt, 1u);
        islast = (old == NBLK - 1) ? 1u : 0u;
    }
    __syncthreads();
    if (islast) {
        __threadfence();
        // device-scope atomic reads (coherent across XCDs), fixed order
        float p = atomicAdd(&lossws[tid], 0.0f) + atomicAdd(&lossws[tid + 256], 0.0f);
        #pragma unroll
        for (int off = 32; off >= 1; off >>= 1) p += __shfl_down(p, off, 64);
        if ((tid & 63) == 0) lred[tid >> 6] = p;
        __syncthreads();
        if (tid == 0)
            out[SQ] = (lred[0] + lred[1] + lred[2] + lred[3]) * (1.0f / (float)SQ);
    }
}

extern "C" void kernel_launch(void* const* d_in, const int* in_sizes, int n_in,
                              void* d_out, int out_size, void* d_ws, size_t ws_size,
                              hipStream_t stream) {
    const float* x = (const float*)d_in[0];     // [128,230]
    const float* y = (const float*)d_in[1];     // [8192,230]
    const int* label = (const int*)d_in[2];     // [128,8192]
    const float* w = (const float*)d_in[3];     // [230]
    const float* b = (const float*)d_in[4];     // [1]
    float* out = (float*)d_out;                 // [128*8192 + 1]

    float* lossws = (float*)d_ws;               // [512]
    unsigned* cnt = (unsigned*)(lossws + NBLK); // [1]

    zero_cnt_kernel<<<1, 64, 0, stream>>>(cnt);
    fused_kernel<<<NBLK, 256, 0, stream>>>(x, y, label, w, b, out, lossws, cnt);
}